// Round 19
// baseline (26.723 us; speedup 1.0000x reference)
//
#include <hip/hip_runtime.h>
#include <hip/hip_bf16.h>
#include <cstdint>

// ProkBertAttention: sliding-window (+-64) attention with RoPE.
// B=4, S=2048, H=12, D=64. fp32 in/out, bf16 MFMA compute.
// Mask input (d_in[3]) ignored: band structure computed analytically.
//
// Round 19 = r16's spill-proof serial staging at QT=128 geometry (the one
// untested cell): 512 thr / 8 waves, grid 768 = 3 blocks/CU (24 waves/CU,
// same occupancy as r16), staged rows/query 3->2 (-33% staging traffic +
// VALU), serial jobs per phase 3+3 -> 2+2 (shorter per-chain stall chain).
// launch_bounds(512,8) (VGPR<=64; r16 compiled clean at this cap with the
// same per-job liveness). Two-phase shared LDS: K [256][64] bf16 XOR
// (32,768B) then V pairs [128][68] u32 (34,816B, rows exact: max kp=127
// with kb=4 lo-only). Data path = r16 verbatim otherwise.
// Ledger: r16 26.62 (best); r18 (256,7) 26.68 neutral; r17 hand-pipeline
// 27.70; r12 27.20; setprio neutral; decomposition 35.3.

typedef short bf16x8 __attribute__((ext_vector_type(8)));
typedef float f32x4  __attribute__((ext_vector_type(4)));
typedef uint32_t u32x4 __attribute__((ext_vector_type(4)));

#define SLEN   2048
#define NHEAD  12
#define NBATCH 4
#define HD     64
#define WHALF  64
#define QT     128         // queries per block (8 waves x 16)
#define KROWS  256         // QT + 2*WHALF
#define NKC    9           // per-wave key chunks (144-key span)
#define VST    68          // V-pair row stride in dwords
#define VROWS  128         // key-pairs (max kp read = 127: kb=4 lo-only)
// scale * log2(e) = (1/8) * 1.4426950408889634 (scores in log2 units)
#define QSCALE 0.18033688011112042f

// Phase 1: sbuf holds K bf16 [256][64] (32,768 B), 16B-chunk XOR (c^(rr&7)).
// Phase 2: sbuf holds V key-paired u32 [128][68] (34,816 B), cell[kp][d] =
//          (bf16 V[2kp][d], V[2kp+1][d]).
// LDS alloc = 34,816 B; grid 768 = 3 blocks/CU = 24 waves/CU; VGPR cap 64.

__device__ __forceinline__ uint32_t cvt_pk(float lo, float hi) {
    // dst[15:0] = bf16(lo), dst[31:16] = bf16(hi); RNE (gfx950)
    uint32_t r;
    asm("v_cvt_pk_bf16_f32 %0, %1, %2" : "=v"(r) : "v"(lo), "v"(hi));
    return r;
}

__global__ __launch_bounds__(512, 8) void prokbert_attn(
        const float* __restrict__ qkv, const float* __restrict__ cosT,
        const float* __restrict__ sinT, float* __restrict__ out)
{
    __shared__ __align__(16) uint32_t sbuf[VROWS * VST];
    short* sKp = (short*)sbuf;

    const int tid = threadIdx.x;

    // ---- XCD-aware block swizzle (768 blocks = 8 XCDs x 96, bijective) ----
    const int bid = blockIdx.x;
    const int gid = (bid & 7) * 96 + (bid >> 3);
    const int qt = gid & 15;          // 16 q-tiles per (b,h)
    const int hh = gid >> 4;          // 0..47 = b*12 + h
    const int h = hh % NHEAD, b = hh / NHEAD;

    const int q0 = qt * QT;
    const int kstart = q0 - WHALF;

    const int wv = tid >> 6;
    const int lane = tid & 63;
    const int r = lane & 15, g = lane >> 4;
    const int rx = r & 7;
    const int qrow = q0 + wv * 16 + r;

    // ========== phase 1: K staging, 2 jobs, STRICTLY SERIAL ==========
    // job (rr, c4) owns d = c4*8..+7 AND +32; rr = rrb + it*128.
    const int rrb = tid >> 2, c4 = tid & 3, d0 = c4 * 8;

    #pragma unroll
    for (int it = 0; it < 2; ++it) {
        const int rr = rrb + it * 128;
        const int s = kstart + rr;
        u32x4 klo = {0, 0, 0, 0}, khi = {0, 0, 0, 0};
        if ((unsigned)s < SLEN) {
            const size_t kbase = (((size_t)(b * SLEN + s) * 3 + 1) * NHEAD + h) * HD;
            const f32x4* gxl = (const f32x4*)(qkv + kbase + d0);
            const f32x4* gxh = (const f32x4*)(qkv + kbase + d0 + 32);
            const f32x4* gc  = (const f32x4*)(cosT + s * HD + d0);  // cos[d+32]==cos[d]
            const f32x4* gs  = (const f32x4*)(sinT + s * HD + d0);
            const f32x4 xl0 = gxl[0], xl1 = gxl[1];
            const f32x4 xh0 = gxh[0], xh1 = gxh[1];
            const f32x4 c0 = gc[0], c1 = gc[1];
            const f32x4 s0 = gs[0], s1 = gs[1];
            // RoPE: lo[d] = x[d]*c - x[d+32]*s ; hi[d+32] = x[d+32]*c + x[d]*s
            klo[0] = cvt_pk(xl0[0]*c0[0]-xh0[0]*s0[0], xl0[1]*c0[1]-xh0[1]*s0[1]);
            klo[1] = cvt_pk(xl0[2]*c0[2]-xh0[2]*s0[2], xl0[3]*c0[3]-xh0[3]*s0[3]);
            klo[2] = cvt_pk(xl1[0]*c1[0]-xh1[0]*s1[0], xl1[1]*c1[1]-xh1[1]*s1[1]);
            klo[3] = cvt_pk(xl1[2]*c1[2]-xh1[2]*s1[2], xl1[3]*c1[3]-xh1[3]*s1[3]);
            khi[0] = cvt_pk(xh0[0]*c0[0]+xl0[0]*s0[0], xh0[1]*c0[1]+xl0[1]*s0[1]);
            khi[1] = cvt_pk(xh0[2]*c0[2]+xl0[2]*s0[2], xh0[3]*c0[3]+xl0[3]*s0[3]);
            khi[2] = cvt_pk(xh1[0]*c1[0]+xl1[0]*s1[0], xh1[1]*c1[1]+xl1[1]*s1[1]);
            khi[3] = cvt_pk(xh1[2]*c1[2]+xl1[2]*s1[2], xh1[3]*c1[3]+xl1[3]*s1[3]);
        }
        const int sw = rr & 7;
        *(u32x4*)&sKp[rr * 64 + ((c4 ^ sw) << 3)]       = klo;
        *(u32x4*)&sKp[rr * 64 + (((c4 + 4) ^ sw) << 3)] = khi;
    }

    // ---- Q load + RoPE + pack, two half-chunks (16 regs live each) ----
    bf16x8 qf0, qf1;           // k-slots: d = g*8+j and 32+g*8+j
    {
        u32x4 w0, w1;
        const size_t qb = (((size_t)(b * SLEN + qrow) * 3 + 0) * NHEAD + h) * HD;
        #pragma unroll
        for (int p = 0; p < 2; ++p) {
            const int dq = g * 8 + p * 4;
            const f32x4 qa = *(const f32x4*)(qkv + qb + dq);
            const f32x4 qbv = *(const f32x4*)(qkv + qb + 32 + dq);
            const f32x4 qc = *(const f32x4*)(cosT + (size_t)qrow * HD + dq);
            const f32x4 qs = *(const f32x4*)(sinT + (size_t)qrow * HD + dq);
            w0[2*p]   = cvt_pk((qa[0]*qc[0]-qbv[0]*qs[0])*QSCALE,
                               (qa[1]*qc[1]-qbv[1]*qs[1])*QSCALE);
            w0[2*p+1] = cvt_pk((qa[2]*qc[2]-qbv[2]*qs[2])*QSCALE,
                               (qa[3]*qc[3]-qbv[3]*qs[3])*QSCALE);
            w1[2*p]   = cvt_pk((qbv[0]*qc[0]+qa[0]*qs[0])*QSCALE,
                               (qbv[1]*qc[1]+qa[1]*qs[1])*QSCALE);
            w1[2*p+1] = cvt_pk((qbv[2]*qc[2]+qa[2]*qs[2])*QSCALE,
                               (qbv[3]*qc[3]+qa[3]*qs[3])*QSCALE);
        }
        qf0 = __builtin_bit_cast(bf16x8, w0);
        qf1 = __builtin_bit_cast(bf16x8, w1);
    }
    __syncthreads();   // bar1: K staged

    // ===== fused QK^T -> mask -> exp -> P-pack (deferred norm) =====
    // S^T = mfma(K_chunk, Q): C row = key-in-chunk = 4g+i, C col = query = r.
    // Wave wv spans keys [wv*16, wv*16+144) in sK row space. Band mask only
    // at kc=0 (4g+i<r) and kc=8 (4g+i>r); zero K rows give score 0 -> e=1,
    // V=0: denominator fixed analytically below.
    // paw k-slot map: key(g,j) = kb*32 + (j>>2)*16 + 4g + (j&3).
    u32x4 paw[5];
    float sum = 0.f;
    const int tg = 4 * g;
    #pragma unroll
    for (int kc = 0; kc < NKC; ++kc) {
        const int row = wv * 16 + kc * 16 + r;
        const bf16x8 ka0 = *(const bf16x8*)&sKp[row * 64 + ((g ^ rx) << 3)];
        const bf16x8 ka1 = *(const bf16x8*)&sKp[row * 64 + (((g + 4) ^ rx) << 3)];
        f32x4 c = {0.f, 0.f, 0.f, 0.f};
        c = __builtin_amdgcn_mfma_f32_16x16x32_bf16(ka0, qf0, c, 0, 0, 0);
        c = __builtin_amdgcn_mfma_f32_16x16x32_bf16(ka1, qf1, c, 0, 0, 0);
        f32x4 e;
        #pragma unroll
        for (int i = 0; i < 4; ++i) {
            float ev = exp2f(c[i]);   // scores already in log2 units
            if (kc == 0) ev = (tg + i >= r) ? ev : 0.f;
            if (kc == 8) ev = (tg + i <= r) ? ev : 0.f;
            e[i] = ev;
            sum += ev;
        }
        const uint32_t wlo = cvt_pk(e[0], e[1]);
        const uint32_t whi = cvt_pk(e[2], e[3]);
        if ((kc & 1) == 0) { paw[kc >> 1][0] = wlo; paw[kc >> 1][1] = whi; }
        else               { paw[kc >> 1][2] = wlo; paw[kc >> 1][3] = whi; }
    }
    paw[4][2] = 0; paw[4][3] = 0;

    sum += __shfl_xor(sum, 16);
    sum += __shfl_xor(sum, 32);
    const int oob = max(0, WHALF - qrow) + max(0, qrow - (SLEN - 1 - WHALF));
    const float inv = 1.f / (sum - (float)oob);

    __syncthreads();   // bar2: all K reads done; sbuf free for V

    // ========== phase 2: V staging, 2 jobs, STRICTLY SERIAL ==========
    // job j = tid + it*512: kp = j>>3 in [0,128), c8 = j&7 -> d = c8*8..+7.
    #pragma unroll
    for (int it = 0; it < 2; ++it) {
        const int j = tid + it * 512;
        const int kp = j >> 3, dd = (j & 7) * 8;
        const int s0 = kstart + 2 * kp, s1 = s0 + 1;
        const f32x4 z = {0.f, 0.f, 0.f, 0.f};
        f32x4 va0 = z, va1 = z, vb0 = z, vb1 = z;
        if ((unsigned)s0 < SLEN) {
            const f32x4* g0 = (const f32x4*)(qkv +
                (((size_t)(b * SLEN + s0) * 3 + 2) * NHEAD + h) * HD + dd);
            va0 = g0[0]; va1 = g0[1];
        }
        if ((unsigned)s1 < SLEN) {
            const f32x4* g1 = (const f32x4*)(qkv +
                (((size_t)(b * SLEN + s1) * 3 + 2) * NHEAD + h) * HD + dd);
            vb0 = g1[0]; vb1 = g1[1];
        }
        u32x4 w0, w1;
        w0[0] = cvt_pk(va0[0], vb0[0]); w0[1] = cvt_pk(va0[1], vb0[1]);
        w0[2] = cvt_pk(va0[2], vb0[2]); w0[3] = cvt_pk(va0[3], vb0[3]);
        w1[0] = cvt_pk(va1[0], vb1[0]); w1[1] = cvt_pk(va1[1], vb1[1]);
        w1[2] = cvt_pk(va1[2], vb1[2]); w1[3] = cvt_pk(va1[3], vb1[3]);
        *(u32x4*)&sbuf[kp * VST + dd]     = w0;
        *(u32x4*)&sbuf[kp * VST + dd + 4] = w1;
    }
    __syncthreads();   // bar3: V staged

    // ================= O = P x V (paired-key u32 reads) =================
    // kb<4: keys kb*32 + {0,1,2,3,16,17,18,19} + 4g (pairs +0,+1,+8,+9).
    // kb=4: lo half only (hi pa==0 -> w[2]=w[3]=0, no LDS read; max kp=127).
    const uint32_t* vptr = &sbuf[(wv * 8 + 2 * g) * VST + r];
    f32x4 oacc[4] = {{0,0,0,0},{0,0,0,0},{0,0,0,0},{0,0,0,0}};
    #pragma unroll
    for (int kb = 0; kb < 5; ++kb) {
        const bf16x8 pa = __builtin_bit_cast(bf16x8, paw[kb]);
        #pragma unroll
        for (int dc = 0; dc < 4; ++dc) {
            const int base = kb * 16 * VST + dc * 16;
            u32x4 w;
            w[0] = vptr[base];                 // keys kb*32+4g, +1
            w[1] = vptr[base + VST];           // +2, +3
            if (kb < 4) {
                w[2] = vptr[base + 8 * VST];   // +16, +17
                w[3] = vptr[base + 9 * VST];   // +18, +19
            } else {
                w[2] = 0; w[3] = 0;            // pa hi == 0; avoid OOB read
            }
            const bf16x8 vbf = __builtin_bit_cast(bf16x8, w);
            oacc[dc] = __builtin_amdgcn_mfma_f32_16x16x32_bf16(pa, vbf, oacc[dc], 0, 0, 0);
        }
    }

    // ---- store (C row = query = g*4+i, col = d = r), deferred norm ----
    #pragma unroll
    for (int i = 0; i < 4; ++i) {
        const float iq = __shfl(inv, g * 4 + i);   // inv depends only on lane&15
        const int qg = q0 + wv * 16 + g * 4 + i;
        float* orow = out + (((size_t)(b * SLEN + qg)) * NHEAD + h) * HD + r;
        orow[0]  = oacc[0][i] * iq;
        orow[16] = oacc[1][i] * iq;
        orow[32] = oacc[2][i] * iq;
        orow[48] = oacc[3][i] * iq;
    }
}

extern "C" void kernel_launch(void* const* d_in, const int* in_sizes, int n_in,
                              void* d_out, int out_size, void* d_ws, size_t ws_size,
                              hipStream_t stream) {
    const float* qkv  = (const float*)d_in[0];
    const float* cosT = (const float*)d_in[1];
    const float* sinT = (const float*)d_in[2];
    // d_in[3] = mask: unused (band structure computed analytically)
    float* out = (float*)d_out;
    dim3 grid(16 * NHEAD * NBATCH);   // 768 = 3 blocks/CU x 256 CUs, no tail
    dim3 block(512);
    hipLaunchKernelGGL(prokbert_attn, grid, block, 0, stream, qkv, cosT, sinT, out);
}